// Round 1
// baseline (713.971 us; speedup 1.0000x reference)
//
#include <hip/hip_runtime.h>
#include <math.h>

#define BB 8
#define NN 4096
#define MM 4000
#define KK 5

#define ACC_ROT    0
#define ACC_TRANS  1
#define ACC_ALIGN  2
#define ACC_DISP   3
#define ACC_DEFORM 4
#define ACC_LAP    5
#define ACC_RMSE   6   // 8 entries, per batch
#define ACC_COUNT  16

__device__ __forceinline__ float waveReduceSum(float v) {
#pragma unroll
    for (int off = 32; off > 0; off >>= 1) v += __shfl_down(v, off, 64);
    return v;
}

// K1: zero accumulators + rotation/translation losses (tiny)
__global__ void k_small(const float* __restrict__ Rp, const float* __restrict__ tp,
                        const float* __restrict__ Rg, const float* __restrict__ tg,
                        float* __restrict__ acc) {
    int tid = threadIdx.x;
    if (tid < ACC_COUNT) acc[tid] = 0.f;
    __syncthreads();
    if (tid < BB) {
        int b = tid;
        float tr = 0.f;
#pragma unroll
        for (int i = 0; i < 9; ++i) tr += Rp[b * 9 + i] * Rg[b * 9 + i];
        float c = (tr - 1.f) * 0.5f;
        c = fminf(fmaxf(c, -1.f + 1e-7f), 1.f - 1e-7f);
        float lrot = acosf(c);
        float dx = tp[b * 3 + 0] - tg[b * 3 + 0];
        float dy = tp[b * 3 + 1] - tg[b * 3 + 1];
        float dz = tp[b * 3 + 2] - tg[b * 3 + 2];
        float ltr = sqrtf(dx * dx + dy * dy + dz * dz);
        atomicAdd(&acc[ACC_ROT], lrot);
        atomicAdd(&acc[ACC_TRANS], ltr);
    }
}

// K2: Y_rigid = Y@Rp^T + tp (stored), rmse partial per batch, disp partial
__global__ void k_rigid(const float* __restrict__ Y, const float* __restrict__ Rp,
                        const float* __restrict__ tp, const float* __restrict__ Rg,
                        const float* __restrict__ tg, const float* __restrict__ dl,
                        float* __restrict__ Yr, float* __restrict__ acc) {
    int b = blockIdx.x >> 4;                       // 16 blocks of 256 per batch
    int n = ((blockIdx.x & 15) << 8) + threadIdx.x;
    size_t base = ((size_t)b * NN + n) * 3;
    float yx = Y[base + 0], yy = Y[base + 1], yz = Y[base + 2];

    float rp[9], rg[9], tpv[3], tgv[3];
#pragma unroll
    for (int i = 0; i < 9; ++i) { rp[i] = Rp[b * 9 + i]; rg[i] = Rg[b * 9 + i]; }
#pragma unroll
    for (int i = 0; i < 3; ++i) { tpv[i] = tp[b * 3 + i]; tgv[i] = tg[b * 3 + i]; }

    float dr2 = 0.f;
#pragma unroll
    for (int k = 0; k < 3; ++k) {
        float p = fmaf(yx, rp[k * 3 + 0], fmaf(yy, rp[k * 3 + 1], fmaf(yz, rp[k * 3 + 2], tpv[k])));
        float g = fmaf(yx, rg[k * 3 + 0], fmaf(yy, rg[k * 3 + 1], fmaf(yz, rg[k * 3 + 2], tgv[k])));
        Yr[base + k] = p;
        float dd = p - g;
        dr2 = fmaf(dd, dd, dr2);
    }
    float d0 = dl[base + 0], d1 = dl[base + 1], d2v = dl[base + 2];
    float dsq = d0 * d0 + d1 * d1 + d2v * d2v;

    dr2 = waveReduceSum(dr2);
    dsq = waveReduceSum(dsq);
    if ((threadIdx.x & 63) == 0) {
        atomicAdd(&acc[ACC_RMSE + b], dr2);
        atomicAdd(&acc[ACC_DISP], dsq);
    }
}

// K3: L_align — for each X_hat[b,n], sum of 5 smallest sq-dists to X[b,:]
#define ATILE 1000
__global__ void k_align(const float* __restrict__ Xh, const float* __restrict__ X,
                        float* __restrict__ acc) {
    __shared__ float4 sc[ATILE];
    int b = blockIdx.y;
    int n = blockIdx.x * blockDim.x + threadIdx.x;
    size_t qb = ((size_t)b * NN + n) * 3;
    float qx = Xh[qb + 0], qy = Xh[qb + 1], qz = Xh[qb + 2];
    float qn = qx * qx + qy * qy + qz * qz;

    float b0 = __FLT_MAX__, b1 = __FLT_MAX__, b2 = __FLT_MAX__, b3 = __FLT_MAX__, b4 = __FLT_MAX__;

    for (int t = 0; t < MM; t += ATILE) {
        __syncthreads();
        for (int i = threadIdx.x; i < ATILE; i += blockDim.x) {
            size_t cb = ((size_t)b * MM + t + i) * 3;
            float x0 = X[cb + 0], x1 = X[cb + 1], x2 = X[cb + 2];
            sc[i] = make_float4(x0, x1, x2, x0 * x0 + x1 * x1 + x2 * x2);
        }
        __syncthreads();
#pragma unroll 4
        for (int j = 0; j < ATILE; ++j) {
            float4 c = sc[j];
            float dot = fmaf(qx, c.x, fmaf(qy, c.y, qz * c.z));
            float d = fmaf(-2.f, dot, qn + c.w);
            d = fmaxf(d, 0.f);
            if (d < b4) {
                b4 = d;
                if (b4 < b3) { float u = b3; b3 = b4; b4 = u; }
                if (b3 < b2) { float u = b2; b2 = b3; b3 = u; }
                if (b2 < b1) { float u = b1; b1 = b2; b2 = u; }
                if (b1 < b0) { float u = b0; b0 = b1; b1 = u; }
            }
        }
    }
    float s = b0 + b1 + b2 + b3 + b4;
    s = waveReduceSum(s);
    if ((threadIdx.x & 63) == 0) atomicAdd(&acc[ACC_ALIGN], s);
}

// K4: kNN graph on Y_rigid (excl. self) + L_deform + L_lap contributions
#define KTILE 1024
__global__ void k_knn(const float* __restrict__ Yr, const float* __restrict__ Xh,
                      const float* __restrict__ dl, float* __restrict__ acc) {
    __shared__ float4 sc[KTILE];
    int b = blockIdx.y;
    int n = blockIdx.x * blockDim.x + threadIdx.x;
    const float* yrb = Yr + (size_t)b * NN * 3;
    float qx = yrb[n * 3 + 0], qy = yrb[n * 3 + 1], qz = yrb[n * 3 + 2];
    float qn = qx * qx + qy * qy + qz * qz;

    float b0 = __FLT_MAX__, b1 = __FLT_MAX__, b2 = __FLT_MAX__, b3 = __FLT_MAX__, b4 = __FLT_MAX__;
    int i0 = 0, i1 = 0, i2 = 0, i3 = 0, i4 = 0;

    for (int t = 0; t < NN; t += KTILE) {
        __syncthreads();
        for (int i = threadIdx.x; i < KTILE; i += blockDim.x) {
            const float* yp = yrb + (size_t)(t + i) * 3;
            float x0 = yp[0], x1 = yp[1], x2 = yp[2];
            sc[i] = make_float4(x0, x1, x2, x0 * x0 + x1 * x1 + x2 * x2);
        }
        __syncthreads();
#pragma unroll 4
        for (int j = 0; j < KTILE; ++j) {
            int m = t + j;
            float4 c = sc[j];
            float dot = fmaf(qx, c.x, fmaf(qy, c.y, qz * c.z));
            float d = fmaf(-2.f, dot, qn + c.w);
            d = fmaxf(d, 0.f);
            if (d < b4 && m != n) {
                b4 = d; i4 = m;
                if (b4 < b3) { float u = b3; b3 = b4; b4 = u; int v = i3; i3 = i4; i4 = v; }
                if (b3 < b2) { float u = b2; b2 = b3; b3 = u; int v = i2; i2 = i3; i3 = v; }
                if (b2 < b1) { float u = b1; b1 = b2; b2 = u; int v = i1; i1 = i2; i2 = v; }
                if (b1 < b0) { float u = b0; b0 = b1; b1 = u; int v = i0; i0 = i1; i1 = v; }
            }
        }
    }

    const float* xh = Xh + (size_t)b * NN * 3;
    const float* dlb = dl + (size_t)b * NN * 3;
    float xnx = xh[n * 3 + 0], xny = xh[n * 3 + 1], xnz = xh[n * 3 + 2];
    float dnx = dlb[n * 3 + 0], dny = dlb[n * 3 + 1], dnz = dlb[n * 3 + 2];

    float def = 0.f, sx = 0.f, sy = 0.f, sz = 0.f;
    int ids[5] = { i0, i1, i2, i3, i4 };
#pragma unroll
    for (int k = 0; k < 5; ++k) {
        int j = ids[k];
        float ex = (xh[j * 3 + 0] - xnx) - (yrb[j * 3 + 0] - qx);
        float ey = (xh[j * 3 + 1] - xny) - (yrb[j * 3 + 1] - qy);
        float ez = (xh[j * 3 + 2] - xnz) - (yrb[j * 3 + 2] - qz);
        def += ex * ex + ey * ey + ez * ez;
        sx += dlb[j * 3 + 0]; sy += dlb[j * 3 + 1]; sz += dlb[j * 3 + 2];
    }
    float lx = dnx - sx / 5.f, ly = dny - sy / 5.f, lz = dnz - sz / 5.f;
    float lap = lx * lx + ly * ly + lz * lz;

    def = waveReduceSum(def);
    lap = waveReduceSum(lap);
    if ((threadIdx.x & 63) == 0) {
        atomicAdd(&acc[ACC_DEFORM], def);
        atomicAdd(&acc[ACC_LAP], lap);
    }
}

// K5: combine
__global__ void k_final(const float* __restrict__ acc, float* __restrict__ out) {
    if (threadIdx.x == 0 && blockIdx.x == 0) {
        float L_rot = acc[ACC_ROT] / BB;
        float L_trans = acc[ACC_TRANS] / BB;
        float L_rmse = 0.f;
        for (int b = 0; b < BB; ++b) L_rmse += sqrtf(acc[ACC_RMSE + b] / NN);
        L_rmse /= BB;
        float L_align = acc[ACC_ALIGN] / ((float)BB * NN * KK);
        float L_disp = acc[ACC_DISP] / ((float)BB * NN);
        float L_def = acc[ACC_DEFORM] / ((float)BB * NN * KK);
        float L_lap = acc[ACC_LAP] / ((float)BB * NN);
        float rigid = L_rot + L_trans + L_rmse;
        float nr = L_align + 0.01f * L_disp + 0.1f * L_def + 0.1f * L_lap;
        out[0] = rigid + nr;
        out[1] = rigid;
        out[2] = nr;
        out[3] = L_rot;
        out[4] = L_trans;
        out[5] = L_rmse;
        out[6] = L_align;
        out[7] = L_disp;
        out[8] = L_def;
        out[9] = L_lap;
    }
}

extern "C" void kernel_launch(void* const* d_in, const int* in_sizes, int n_in,
                              void* d_out, int out_size, void* d_ws, size_t ws_size,
                              hipStream_t stream) {
    const float* Y  = (const float*)d_in[0];
    const float* X  = (const float*)d_in[1];
    const float* Rp = (const float*)d_in[2];
    const float* tp = (const float*)d_in[3];
    const float* Rg = (const float*)d_in[4];
    const float* tg = (const float*)d_in[5];
    const float* Xh = (const float*)d_in[6];
    const float* dl = (const float*)d_in[7];
    float* out = (float*)d_out;

    float* Yr  = (float*)d_ws;                       // B*N*3 floats
    float* acc = Yr + (size_t)BB * NN * 3;           // 16 floats

    hipLaunchKernelGGL(k_small, dim3(1), dim3(64), 0, stream, Rp, tp, Rg, tg, acc);
    hipLaunchKernelGGL(k_rigid, dim3(BB * NN / 256), dim3(256), 0, stream,
                       Y, Rp, tp, Rg, tg, dl, Yr, acc);
    hipLaunchKernelGGL(k_align, dim3(NN / 128, BB), dim3(128), 0, stream, Xh, X, acc);
    hipLaunchKernelGGL(k_knn, dim3(NN / 128, BB), dim3(128), 0, stream, Yr, Xh, dl, acc);
    hipLaunchKernelGGL(k_final, dim3(1), dim3(1), 0, stream, acc, out);
}

// Round 2
// 192.929 us; speedup vs baseline: 3.7007x; 3.7007x over previous
//
#include <hip/hip_runtime.h>
#include <math.h>

#define BB 8
#define NN 4096
#define MM 4000
#define KK 5

#define NWAVE 8
#define QPB 64
#define KCH (NN / NWAVE)   // 512 candidates per wave-chunk (knn)
#define ACH (MM / NWAVE)   // 500 candidates per wave-chunk (align)

#define ACC_ROT    0
#define ACC_TRANS  1
#define ACC_ALIGN  2
#define ACC_DISP   3
#define ACC_DEFORM 4
#define ACC_LAP    5
#define ACC_RMSE   6   // 8 entries, per batch
#define ACC_COUNT  16

__device__ __forceinline__ float waveReduceSum(float v) {
#pragma unroll
    for (int off = 32; off > 0; off >>= 1) v += __shfl_down(v, off, 64);
    return v;
}

// K1: zero accumulators + rotation/translation losses (tiny)
__global__ void k_small(const float* __restrict__ Rp, const float* __restrict__ tp,
                        const float* __restrict__ Rg, const float* __restrict__ tg,
                        float* __restrict__ acc) {
    int tid = threadIdx.x;
    if (tid < ACC_COUNT) acc[tid] = 0.f;
    __syncthreads();
    if (tid < BB) {
        int b = tid;
        float tr = 0.f;
#pragma unroll
        for (int i = 0; i < 9; ++i) tr += Rp[b * 9 + i] * Rg[b * 9 + i];
        float c = (tr - 1.f) * 0.5f;
        c = fminf(fmaxf(c, -1.f + 1e-7f), 1.f - 1e-7f);
        float lrot = acosf(c);
        float dx = tp[b * 3 + 0] - tg[b * 3 + 0];
        float dy = tp[b * 3 + 1] - tg[b * 3 + 1];
        float dz = tp[b * 3 + 2] - tg[b * 3 + 2];
        float ltr = sqrtf(dx * dx + dy * dy + dz * dz);
        atomicAdd(&acc[ACC_ROT], lrot);
        atomicAdd(&acc[ACC_TRANS], ltr);
    }
}

// K2: Y_rigid = Y@Rp^T + tp (stored), rmse partial per batch, disp partial
__global__ void k_rigid(const float* __restrict__ Y, const float* __restrict__ Rp,
                        const float* __restrict__ tp, const float* __restrict__ Rg,
                        const float* __restrict__ tg, const float* __restrict__ dl,
                        float* __restrict__ Yr, float* __restrict__ acc) {
    int b = blockIdx.x >> 4;
    int n = ((blockIdx.x & 15) << 8) + threadIdx.x;
    size_t base = ((size_t)b * NN + n) * 3;
    float yx = Y[base + 0], yy = Y[base + 1], yz = Y[base + 2];

    float rp[9], rg[9], tpv[3], tgv[3];
#pragma unroll
    for (int i = 0; i < 9; ++i) { rp[i] = Rp[b * 9 + i]; rg[i] = Rg[b * 9 + i]; }
#pragma unroll
    for (int i = 0; i < 3; ++i) { tpv[i] = tp[b * 3 + i]; tgv[i] = tg[b * 3 + i]; }

    float dr2 = 0.f;
#pragma unroll
    for (int k = 0; k < 3; ++k) {
        float p = fmaf(yx, rp[k * 3 + 0], fmaf(yy, rp[k * 3 + 1], fmaf(yz, rp[k * 3 + 2], tpv[k])));
        float g = fmaf(yx, rg[k * 3 + 0], fmaf(yy, rg[k * 3 + 1], fmaf(yz, rg[k * 3 + 2], tgv[k])));
        Yr[base + k] = p;
        float dd = p - g;
        dr2 = fmaf(dd, dd, dr2);
    }
    float d0 = dl[base + 0], d1 = dl[base + 1], d2v = dl[base + 2];
    float dsq = d0 * d0 + d1 * d1 + d2v * d2v;

    dr2 = waveReduceSum(dr2);
    dsq = waveReduceSum(dsq);
    if ((threadIdx.x & 63) == 0) {
        atomicAdd(&acc[ACC_RMSE + b], dr2);
        atomicAdd(&acc[ACC_DISP], dsq);
    }
}

// K3: L_align — candidate dim split across 8 waves, LDS merge of sorted top-5 lists
__global__ __launch_bounds__(512) void k_align(const float* __restrict__ Xh,
                                               const float* __restrict__ X,
                                               float* __restrict__ acc) {
    __shared__ float4 sc[NWAVE][64];
    __shared__ float md[NWAVE][QPB][6];

    int tid = threadIdx.x;
    int wave = tid >> 6, lane = tid & 63;
    int b = blockIdx.y;
    int q = blockIdx.x * QPB + lane;
    size_t qb = ((size_t)b * NN + q) * 3;
    float qx = Xh[qb + 0], qy = Xh[qb + 1], qz = Xh[qb + 2];
    float qn = fmaf(qx, qx, fmaf(qy, qy, qz * qz));

    float b0 = __FLT_MAX__, b1 = __FLT_MAX__, b2 = __FLT_MAX__, b3 = __FLT_MAX__, b4 = __FLT_MAX__;
    int tc = wave * ACH;
    const float* xb = X + (size_t)b * MM * 3;

    for (int t0 = 0; t0 < ACH; t0 += 64) {
        __syncthreads();
        {
            int m = tc + t0 + lane;
            m = m < MM ? m : MM - 1;                 // clamp (tail tile)
            float x0 = xb[m * 3 + 0], x1 = xb[m * 3 + 1], x2 = xb[m * 3 + 2];
            sc[wave][lane] = make_float4(x0, x1, x2, fmaf(x0, x0, fmaf(x1, x1, x2 * x2)));
        }
        __syncthreads();
        int lim = ACH - t0;                          // valid j in this tile
#pragma unroll 8
        for (int j = 0; j < 64; ++j) {
            float4 c = sc[wave][j];
            float dot = fmaf(qx, c.x, fmaf(qy, c.y, qz * c.z));
            float d = fmaf(-2.f, dot, qn + c.w);
            d = fmaxf(d, 0.f);
            if (d < b4 && j < lim) {
                b4 = d;
                if (b4 < b3) { float u = b3; b3 = b4; b4 = u; }
                if (b3 < b2) { float u = b2; b2 = b3; b3 = u; }
                if (b2 < b1) { float u = b1; b1 = b2; b2 = u; }
                if (b1 < b0) { float u = b0; b0 = b1; b1 = u; }
            }
        }
    }

    md[wave][lane][0] = b0; md[wave][lane][1] = b1; md[wave][lane][2] = b2;
    md[wave][lane][3] = b3; md[wave][lane][4] = b4; md[wave][lane][5] = __FLT_MAX__;
    __syncthreads();

    if (tid < QPB) {
        int l = tid;
        int pp[NWAVE] = {0, 0, 0, 0, 0, 0, 0, 0};
        float s = 0.f;
#pragma unroll
        for (int k = 0; k < KK; ++k) {
            float best = __FLT_MAX__;
            int bw = 0;
#pragma unroll
            for (int w = 0; w < NWAVE; ++w) {
                float d = md[w][l][pp[w]];
                if (d < best) { best = d; bw = w; }
            }
            s += best;
#pragma unroll
            for (int w = 0; w < NWAVE; ++w) pp[w] += (bw == w) ? 1 : 0;
        }
        s = waveReduceSum(s);
        if (l == 0) atomicAdd(&acc[ACC_ALIGN], s);
    }
}

// K4: kNN graph on Y_rigid (excl. self), split+merge, then deform/lap epilogue
__global__ __launch_bounds__(512) void k_knn(const float* __restrict__ Yr,
                                             const float* __restrict__ Xh,
                                             const float* __restrict__ dl,
                                             float* __restrict__ acc) {
    __shared__ float4 sc[NWAVE][64];
    __shared__ float md[NWAVE][QPB][6];
    __shared__ int   mi[NWAVE][QPB][6];

    int tid = threadIdx.x;
    int wave = tid >> 6, lane = tid & 63;
    int b = blockIdx.y;
    int q = blockIdx.x * QPB + lane;
    const float* yrb = Yr + (size_t)b * NN * 3;

    float qx = yrb[q * 3 + 0], qy = yrb[q * 3 + 1], qz = yrb[q * 3 + 2];
    float qn = fmaf(qx, qx, fmaf(qy, qy, qz * qz));

    float b0 = __FLT_MAX__, b1 = __FLT_MAX__, b2 = __FLT_MAX__, b3 = __FLT_MAX__, b4 = __FLT_MAX__;
    int i0 = 0x7fffffff, i1 = 0x7fffffff, i2 = 0x7fffffff, i3 = 0x7fffffff, i4 = 0x7fffffff;
    int tc = wave * KCH;

    for (int t0 = 0; t0 < KCH; t0 += 64) {
        __syncthreads();
        {
            int m = tc + t0 + lane;
            float x0 = yrb[m * 3 + 0], x1 = yrb[m * 3 + 1], x2 = yrb[m * 3 + 2];
            sc[wave][lane] = make_float4(x0, x1, x2, fmaf(x0, x0, fmaf(x1, x1, x2 * x2)));
        }
        __syncthreads();
#pragma unroll 8
        for (int j = 0; j < 64; ++j) {
            float4 c = sc[wave][j];
            int m = tc + t0 + j;
            float dot = fmaf(qx, c.x, fmaf(qy, c.y, qz * c.z));
            float d = fmaf(-2.f, dot, qn + c.w);
            d = fmaxf(d, 0.f);
            if (d < b4 && m != q) {
                b4 = d; i4 = m;
                if (b4 < b3) { float u = b3; b3 = b4; b4 = u; int v = i3; i3 = i4; i4 = v; }
                if (b3 < b2) { float u = b2; b2 = b3; b3 = u; int v = i2; i2 = i3; i3 = v; }
                if (b2 < b1) { float u = b1; b1 = b2; b2 = u; int v = i1; i1 = i2; i2 = v; }
                if (b1 < b0) { float u = b0; b0 = b1; b1 = u; int v = i0; i0 = i1; i1 = v; }
            }
        }
    }

    md[wave][lane][0] = b0; md[wave][lane][1] = b1; md[wave][lane][2] = b2;
    md[wave][lane][3] = b3; md[wave][lane][4] = b4; md[wave][lane][5] = __FLT_MAX__;
    mi[wave][lane][0] = i0; mi[wave][lane][1] = i1; mi[wave][lane][2] = i2;
    mi[wave][lane][3] = i3; mi[wave][lane][4] = i4; mi[wave][lane][5] = 0x7fffffff;
    __syncthreads();

    if (tid < QPB) {
        int l = tid;
        int pp[NWAVE] = {0, 0, 0, 0, 0, 0, 0, 0};
        int si[KK];
#pragma unroll
        for (int k = 0; k < KK; ++k) {
            float best = __FLT_MAX__;
            int besti = 0x7fffffff;
            int bw = 0;
#pragma unroll
            for (int w = 0; w < NWAVE; ++w) {
                float d = md[w][l][pp[w]];
                int ii = mi[w][l][pp[w]];
                if (d < best || (d == best && ii < besti)) { best = d; besti = ii; bw = w; }
            }
            si[k] = besti;
#pragma unroll
            for (int w = 0; w < NWAVE; ++w) pp[w] += (bw == w) ? 1 : 0;
        }

        const float* xh = Xh + (size_t)b * NN * 3;
        const float* dlb = dl + (size_t)b * NN * 3;
        float xnx = xh[q * 3 + 0], xny = xh[q * 3 + 1], xnz = xh[q * 3 + 2];
        float dnx = dlb[q * 3 + 0], dny = dlb[q * 3 + 1], dnz = dlb[q * 3 + 2];

        float def = 0.f, sx = 0.f, sy = 0.f, sz = 0.f;
#pragma unroll
        for (int k = 0; k < KK; ++k) {
            int j = si[k];
            float ex = (xh[j * 3 + 0] - xnx) - (yrb[j * 3 + 0] - qx);
            float ey = (xh[j * 3 + 1] - xny) - (yrb[j * 3 + 1] - qy);
            float ez = (xh[j * 3 + 2] - xnz) - (yrb[j * 3 + 2] - qz);
            def += ex * ex + ey * ey + ez * ez;
            sx += dlb[j * 3 + 0]; sy += dlb[j * 3 + 1]; sz += dlb[j * 3 + 2];
        }
        float lx = dnx - sx / 5.f, ly = dny - sy / 5.f, lz = dnz - sz / 5.f;
        float lap = lx * lx + ly * ly + lz * lz;

        def = waveReduceSum(def);
        lap = waveReduceSum(lap);
        if (l == 0) {
            atomicAdd(&acc[ACC_DEFORM], def);
            atomicAdd(&acc[ACC_LAP], lap);
        }
    }
}

// K5: combine
__global__ void k_final(const float* __restrict__ acc, float* __restrict__ out) {
    if (threadIdx.x == 0 && blockIdx.x == 0) {
        float L_rot = acc[ACC_ROT] / BB;
        float L_trans = acc[ACC_TRANS] / BB;
        float L_rmse = 0.f;
        for (int b = 0; b < BB; ++b) L_rmse += sqrtf(acc[ACC_RMSE + b] / NN);
        L_rmse /= BB;
        float L_align = acc[ACC_ALIGN] / ((float)BB * NN * KK);
        float L_disp = acc[ACC_DISP] / ((float)BB * NN);
        float L_def = acc[ACC_DEFORM] / ((float)BB * NN * KK);
        float L_lap = acc[ACC_LAP] / ((float)BB * NN);
        float rigid = L_rot + L_trans + L_rmse;
        float nr = L_align + 0.01f * L_disp + 0.1f * L_def + 0.1f * L_lap;
        out[0] = rigid + nr;
        out[1] = rigid;
        out[2] = nr;
        out[3] = L_rot;
        out[4] = L_trans;
        out[5] = L_rmse;
        out[6] = L_align;
        out[7] = L_disp;
        out[8] = L_def;
        out[9] = L_lap;
    }
}

extern "C" void kernel_launch(void* const* d_in, const int* in_sizes, int n_in,
                              void* d_out, int out_size, void* d_ws, size_t ws_size,
                              hipStream_t stream) {
    const float* Y  = (const float*)d_in[0];
    const float* X  = (const float*)d_in[1];
    const float* Rp = (const float*)d_in[2];
    const float* tp = (const float*)d_in[3];
    const float* Rg = (const float*)d_in[4];
    const float* tg = (const float*)d_in[5];
    const float* Xh = (const float*)d_in[6];
    const float* dl = (const float*)d_in[7];
    float* out = (float*)d_out;

    float* Yr  = (float*)d_ws;                       // B*N*3 floats
    float* acc = Yr + (size_t)BB * NN * 3;           // 16 floats

    hipLaunchKernelGGL(k_small, dim3(1), dim3(64), 0, stream, Rp, tp, Rg, tg, acc);
    hipLaunchKernelGGL(k_rigid, dim3(BB * NN / 256), dim3(256), 0, stream,
                       Y, Rp, tp, Rg, tg, dl, Yr, acc);
    hipLaunchKernelGGL(k_align, dim3(NN / QPB, BB), dim3(512), 0, stream, Xh, X, acc);
    hipLaunchKernelGGL(k_knn, dim3(NN / QPB, BB), dim3(512), 0, stream, Yr, Xh, dl, acc);
    hipLaunchKernelGGL(k_final, dim3(1), dim3(1), 0, stream, acc, out);
}

// Round 3
// 150.899 us; speedup vs baseline: 4.7315x; 1.2785x over previous
//
#include <hip/hip_runtime.h>
#include <math.h>

#define BB 8
#define NN 4096
#define MM 4000
#define KK 5
#define NWAVE 8
#define QPB 64
#define CH 512
#define NPAD 4096
#define KNN_BLOCKS ((NN / QPB) * BB)   // 512

#define ACC_ROT    0
#define ACC_TRANS  1
#define ACC_ALIGN  2
#define ACC_DISP   3
#define ACC_DEFORM 4
#define ACC_LAP    5
#define ACC_RMSE   6   // 8 entries
#define ACC_COUNT  14

__device__ __forceinline__ float waveReduceSum(float v) {
#pragma unroll
    for (int off = 32; off > 0; off >>= 1) v += __shfl_down(v, off, 64);
    return v;
}

// Branchless scan of one 512-candidate chunk. Candidates are wave-uniform:
// readfirstlane forces scalar (SMEM) loads. Top-5 kept in a sorted min/max
// network (9 VALU/candidate, no branches). PACK: index in low 12 mantissa bits.
template<bool SELF, bool PACK>
__device__ __forceinline__ void scan512(const float4* __restrict__ cb, int tc,
                                        float ca, float cbq, float cc, int q,
                                        float& b0, float& b1, float& b2,
                                        float& b3, float& b4) {
    for (int t0 = 0; t0 < CH; t0 += 8) {
        int base = __builtin_amdgcn_readfirstlane(tc + t0);
#pragma unroll
        for (int j = 0; j < 8; ++j) {
            float4 c = cb[base + j];
            float sc = fmaf(c.x, ca, fmaf(c.y, cbq, fmaf(c.z, cc, c.w)));
            float v;
            if (PACK) {
                int m = base + j;
                unsigned pk = (__float_as_uint(sc) & 0xFFFFF000u) | (unsigned)m;
                v = __uint_as_float(pk);
                if (SELF) v = (m == q) ? __int_as_float(0x7F800000) : v;
            } else {
                v = sc;
            }
            float t;
            b4 = fminf(b4, v);
            t = b3; b3 = fminf(t, b4); b4 = fmaxf(t, b4);
            t = b2; b2 = fminf(t, b3); b3 = fmaxf(t, b3);
            t = b1; b1 = fminf(t, b2); b2 = fmaxf(t, b2);
            t = b0; b0 = fminf(t, b1); b1 = fmaxf(t, b1);
        }
    }
}

// K1: Y_rigid (padded float4 + norm), X padded float4 + norm, rmse/disp partials,
// rot/trans losses (one thread per batch).
__global__ void k_prep(const float* __restrict__ Y, const float* __restrict__ X,
                       const float* __restrict__ Rp, const float* __restrict__ tp,
                       const float* __restrict__ Rg, const float* __restrict__ tg,
                       const float* __restrict__ dl,
                       float4* __restrict__ YrP, float4* __restrict__ XP,
                       float* __restrict__ acc) {
    int b = blockIdx.x >> 4;
    int n = ((blockIdx.x & 15) << 8) + threadIdx.x;
    size_t base = ((size_t)b * NN + n) * 3;
    float yx = Y[base + 0], yy = Y[base + 1], yz = Y[base + 2];

    float rp[9], rg[9], tpv[3], tgv[3];
#pragma unroll
    for (int i = 0; i < 9; ++i) { rp[i] = Rp[b * 9 + i]; rg[i] = Rg[b * 9 + i]; }
#pragma unroll
    for (int i = 0; i < 3; ++i) { tpv[i] = tp[b * 3 + i]; tgv[i] = tg[b * 3 + i]; }

    float p[3], dr2 = 0.f;
#pragma unroll
    for (int k = 0; k < 3; ++k) {
        float pv = fmaf(yx, rp[k * 3 + 0], fmaf(yy, rp[k * 3 + 1], fmaf(yz, rp[k * 3 + 2], tpv[k])));
        float gv = fmaf(yx, rg[k * 3 + 0], fmaf(yy, rg[k * 3 + 1], fmaf(yz, rg[k * 3 + 2], tgv[k])));
        p[k] = pv;
        float dd = pv - gv;
        dr2 = fmaf(dd, dd, dr2);
    }
    YrP[(size_t)b * NPAD + n] =
        make_float4(p[0], p[1], p[2], fmaf(p[0], p[0], fmaf(p[1], p[1], p[2] * p[2])));

    float4 xe;
    if (n < MM) {
        size_t xb = ((size_t)b * MM + n) * 3;
        float x0 = X[xb + 0], x1 = X[xb + 1], x2 = X[xb + 2];
        xe = make_float4(x0, x1, x2, fmaf(x0, x0, fmaf(x1, x1, x2 * x2)));
    } else {
        xe = make_float4(0.f, 0.f, 0.f, __int_as_float(0x7F800000));
    }
    XP[(size_t)b * NPAD + n] = xe;

    float d0 = dl[base + 0], d1 = dl[base + 1], d2 = dl[base + 2];
    float dsq = d0 * d0 + d1 * d1 + d2 * d2;

    dr2 = waveReduceSum(dr2);
    dsq = waveReduceSum(dsq);
    if ((threadIdx.x & 63) == 0) {
        atomicAdd(&acc[ACC_RMSE + b], dr2);
        atomicAdd(&acc[ACC_DISP], dsq);
    }

    if (threadIdx.x == 0 && (blockIdx.x & 15) == 0) {
        float tr = 0.f;
#pragma unroll
        for (int i = 0; i < 9; ++i) tr += rp[i] * rg[i];
        float c = (tr - 1.f) * 0.5f;
        c = fminf(fmaxf(c, -1.f + 1e-7f), 1.f - 1e-7f);
        float dx = tpv[0] - tgv[0], dy = tpv[1] - tgv[1], dz = tpv[2] - tgv[2];
        atomicAdd(&acc[ACC_ROT], acosf(c));
        atomicAdd(&acc[ACC_TRANS], sqrtf(dx * dx + dy * dy + dz * dz));
    }
}

#define MERGE_STEP(W) { float d = md[W][l][pp##W]; if (d < best) { best = d; bw = W; } }
#define MERGE_ADV()  { pp0 += (bw == 0); pp1 += (bw == 1); pp2 += (bw == 2); pp3 += (bw == 3); \
                       pp4 += (bw == 4); pp5 += (bw == 5); pp6 += (bw == 6); pp7 += (bw == 7); }

// K2: L_align — 8 waves each scan a 512-candidate chunk of padded X, merge in LDS.
__global__ __launch_bounds__(512) void k_align(const float* __restrict__ Xh,
                                               const float4* __restrict__ XP,
                                               float* __restrict__ acc) {
    __shared__ float md[NWAVE][QPB][6];
    int tid = threadIdx.x, wave = tid >> 6, lane = tid & 63;
    int b = blockIdx.y;
    int q = blockIdx.x * QPB + lane;
    size_t qb = ((size_t)b * NN + q) * 3;
    float qx = Xh[qb + 0], qy = Xh[qb + 1], qz = Xh[qb + 2];
    float qn = fmaf(qx, qx, fmaf(qy, qy, qz * qz));
    const float4* cb = XP + (size_t)b * NPAD;

    float inf = __int_as_float(0x7F800000);
    float b0 = inf, b1 = inf, b2 = inf, b3 = inf, b4 = inf;
    scan512<false, false>(cb, wave * CH, -2.f * qx, -2.f * qy, -2.f * qz, 0,
                          b0, b1, b2, b3, b4);

    md[wave][lane][0] = b0; md[wave][lane][1] = b1; md[wave][lane][2] = b2;
    md[wave][lane][3] = b3; md[wave][lane][4] = b4; md[wave][lane][5] = inf;
    __syncthreads();

    if (tid < QPB) {
        int l = tid;
        int pp0 = 0, pp1 = 0, pp2 = 0, pp3 = 0, pp4 = 0, pp5 = 0, pp6 = 0, pp7 = 0;
        float s = 0.f;
#pragma unroll
        for (int k = 0; k < KK; ++k) {
            float best = inf; int bw = 0;
            MERGE_STEP(0) MERGE_STEP(1) MERGE_STEP(2) MERGE_STEP(3)
            MERGE_STEP(4) MERGE_STEP(5) MERGE_STEP(6) MERGE_STEP(7)
            s += fmaxf(best + qn, 0.f);   // undo the -qn shift, clamp like reference
            MERGE_ADV()
        }
        s = waveReduceSum(s);
        if (l == 0) atomicAdd(&acc[ACC_ALIGN], s);
    }
}

__device__ void finalize(const float* acc, float* out) {
    float a[ACC_COUNT];
#pragma unroll
    for (int i = 0; i < ACC_COUNT; ++i)
        a[i] = __hip_atomic_load(&acc[i], __ATOMIC_RELAXED, __HIP_MEMORY_SCOPE_AGENT);
    float L_rot = a[ACC_ROT] / BB;
    float L_trans = a[ACC_TRANS] / BB;
    float L_rmse = 0.f;
#pragma unroll
    for (int b = 0; b < BB; ++b) L_rmse += sqrtf(a[ACC_RMSE + b] / NN);
    L_rmse /= BB;
    float L_align = a[ACC_ALIGN] / ((float)BB * NN * KK);
    float L_disp = a[ACC_DISP] / ((float)BB * NN);
    float L_def = a[ACC_DEFORM] / ((float)BB * NN * KK);
    float L_lap = a[ACC_LAP] / ((float)BB * NN);
    float rigid = L_rot + L_trans + L_rmse;
    float nr = L_align + 0.01f * L_disp + 0.1f * L_def + 0.1f * L_lap;
    out[0] = rigid + nr; out[1] = rigid; out[2] = nr;
    out[3] = L_rot; out[4] = L_trans; out[5] = L_rmse;
    out[6] = L_align; out[7] = L_disp; out[8] = L_def; out[9] = L_lap;
}

// K3: kNN graph on Y_rigid (self-excluded), deform/lap epilogue, last-block finalize.
__global__ __launch_bounds__(512) void k_knn(const float4* __restrict__ YrP,
                                             const float* __restrict__ Xh,
                                             const float* __restrict__ dl,
                                             float* __restrict__ acc,
                                             unsigned* __restrict__ doneCnt,
                                             float* __restrict__ out) {
    __shared__ float md[NWAVE][QPB][6];
    int tid = threadIdx.x, wave = tid >> 6, lane = tid & 63;
    int b = blockIdx.y;
    int q = blockIdx.x * QPB + lane;
    const float4* cb = YrP + (size_t)b * NPAD;
    float4 qp = cb[q];

    float inf = __int_as_float(0x7F800000);
    float b0 = inf, b1 = inf, b2 = inf, b3 = inf, b4 = inf;
    bool hasSelf = (wave == (blockIdx.x >> 3));   // only this wave's chunk contains q
    if (hasSelf)
        scan512<true, true>(cb, wave * CH, -2.f * qp.x, -2.f * qp.y, -2.f * qp.z, q,
                            b0, b1, b2, b3, b4);
    else
        scan512<false, true>(cb, wave * CH, -2.f * qp.x, -2.f * qp.y, -2.f * qp.z, q,
                             b0, b1, b2, b3, b4);

    md[wave][lane][0] = b0; md[wave][lane][1] = b1; md[wave][lane][2] = b2;
    md[wave][lane][3] = b3; md[wave][lane][4] = b4; md[wave][lane][5] = inf;
    __syncthreads();

    if (tid < QPB) {
        int l = tid;
        int pp0 = 0, pp1 = 0, pp2 = 0, pp3 = 0, pp4 = 0, pp5 = 0, pp6 = 0, pp7 = 0;
        int si[KK];
#pragma unroll
        for (int k = 0; k < KK; ++k) {
            float best = inf; int bw = 0;
            MERGE_STEP(0) MERGE_STEP(1) MERGE_STEP(2) MERGE_STEP(3)
            MERGE_STEP(4) MERGE_STEP(5) MERGE_STEP(6) MERGE_STEP(7)
            si[k] = (int)(__float_as_uint(best) & 0xFFFu);
            MERGE_ADV()
        }

        const float* xh = Xh + (size_t)b * NN * 3;
        const float* dlb = dl + (size_t)b * NN * 3;
        float xnx = xh[q * 3 + 0], xny = xh[q * 3 + 1], xnz = xh[q * 3 + 2];
        float dnx = dlb[q * 3 + 0], dny = dlb[q * 3 + 1], dnz = dlb[q * 3 + 2];

        float def = 0.f, sx = 0.f, sy = 0.f, sz = 0.f;
#pragma unroll
        for (int k = 0; k < KK; ++k) {
            int j = si[k];
            float4 yj = cb[j];
            float ex = (xh[j * 3 + 0] - xnx) - (yj.x - qp.x);
            float ey = (xh[j * 3 + 1] - xny) - (yj.y - qp.y);
            float ez = (xh[j * 3 + 2] - xnz) - (yj.z - qp.z);
            def += ex * ex + ey * ey + ez * ez;
            sx += dlb[j * 3 + 0]; sy += dlb[j * 3 + 1]; sz += dlb[j * 3 + 2];
        }
        float lx = dnx - sx / 5.f, ly = dny - sy / 5.f, lz = dnz - sz / 5.f;
        float lap = lx * lx + ly * ly + lz * lz;

        def = waveReduceSum(def);
        lap = waveReduceSum(lap);
        if (l == 0) {
            atomicAdd(&acc[ACC_DEFORM], def);
            atomicAdd(&acc[ACC_LAP], lap);
            __threadfence();
            unsigned t = __hip_atomic_fetch_add(doneCnt, 1u, __ATOMIC_ACQ_REL,
                                                __HIP_MEMORY_SCOPE_AGENT);
            if (t == KNN_BLOCKS - 1) finalize(acc, out);
        }
    }
}

extern "C" void kernel_launch(void* const* d_in, const int* in_sizes, int n_in,
                              void* d_out, int out_size, void* d_ws, size_t ws_size,
                              hipStream_t stream) {
    const float* Y  = (const float*)d_in[0];
    const float* X  = (const float*)d_in[1];
    const float* Rp = (const float*)d_in[2];
    const float* tp = (const float*)d_in[3];
    const float* Rg = (const float*)d_in[4];
    const float* tg = (const float*)d_in[5];
    const float* Xh = (const float*)d_in[6];
    const float* dl = (const float*)d_in[7];
    float* out = (float*)d_out;

    float*    acc     = (float*)d_ws;                          // 14 floats
    unsigned* doneCnt = (unsigned*)((char*)d_ws + 64);
    float4*   YrP     = (float4*)((char*)d_ws + 512);          // B*4096 float4
    float4*   XP      = YrP + (size_t)BB * NPAD;               // B*4096 float4

    hipMemsetAsync(d_ws, 0, 512, stream);
    hipLaunchKernelGGL(k_prep, dim3(BB * NN / 256), dim3(256), 0, stream,
                       Y, X, Rp, tp, Rg, tg, dl, YrP, XP, acc);
    hipLaunchKernelGGL(k_align, dim3(NN / QPB, BB), dim3(512), 0, stream, Xh, XP, acc);
    hipLaunchKernelGGL(k_knn, dim3(NN / QPB, BB), dim3(512), 0, stream,
                       YrP, Xh, dl, acc, doneCnt, out);
}